// Round 1
// baseline (119.709 us; speedup 1.0000x reference)
//
#include <hip/hip_runtime.h>

// TwoStageRegressionLoss: fused BCE + duration-aware focal smooth-L1 mean
// reduction over N = 2048*16384 fp32 elements per array (4 input arrays).
// Memory-bound: 537 MB read -> ~85us floor at 6.3 TB/s.

constexpr int BLOCK = 256;
constexpr int GRID  = 2048;   // 256 CUs x 8 blocks; 16 float4 iters/thread at N=33.5M

__device__ __forceinline__ void accum_elem(float pv, float tv, float qv, float sv,
                                           float& accB, float& accR) {
    // --- BCE with torch-style log clamp at -100 ---
    float pc = fminf(fmaxf(pv, 0.0f), 1.0f);
    float tc = fminf(fmaxf(tv, 0.0f), 1.0f);
    float lp  = fmaxf(logf(pc),     -100.0f);   // log(0) = -inf -> clamped to -100
    float l1p = fmaxf(log1pf(-pc),  -100.0f);   // log1p(-1) = -inf -> -100
    accB -= tc * lp + (1.0f - tc) * l1p;
    // --- duration-aware focal smooth-L1 (alpha=0.25, gamma=2, delta=0.5) ---
    float d = fabsf(qv - sv);
    float f = fminf(d + d, 1.0f);               // clip(d/0.5, 0, 1)
    float base = (d < 0.5f) ? (d * d) : (d - 0.25f);  // smooth L1, beta=0.5
    // class weight: round-half-even (matches jnp.round), clamp [0,3], table {1,4,3,2}
    int idx = (int)fminf(fmaxf(rintf(sv), 0.0f), 3.0f);
    float w = (idx == 0) ? 1.0f : (idx == 1) ? 4.0f : (idx == 2) ? 3.0f : 2.0f;
    accR += 0.25f * (f * f) * base * w;
}

__global__ __launch_bounds__(BLOCK) void partial_kernel(
    const float4* __restrict__ bp4, const float4* __restrict__ rp4,
    const float4* __restrict__ bt4, const float4* __restrict__ rt4,
    float* __restrict__ partials, int n4, int n)
{
    float accB = 0.0f, accR = 0.0f;
    const int stride = gridDim.x * blockDim.x;
    for (int i = blockIdx.x * blockDim.x + threadIdx.x; i < n4; i += stride) {
        float4 p = bp4[i];
        float4 t = bt4[i];
        float4 q = rp4[i];
        float4 s = rt4[i];
        accum_elem(p.x, t.x, q.x, s.x, accB, accR);
        accum_elem(p.y, t.y, q.y, s.y, accB, accR);
        accum_elem(p.z, t.z, q.z, s.z, accB, accR);
        accum_elem(p.w, t.w, q.w, s.w, accB, accR);
    }
    // scalar tail (n not multiple of 4) -- handled by block 0 only
    if (blockIdx.x == 0) {
        const float* bp = (const float*)bp4;
        const float* bt = (const float*)bt4;
        const float* rp = (const float*)rp4;
        const float* rt = (const float*)rt4;
        for (int i = n4 * 4 + threadIdx.x; i < n; i += BLOCK)
            accum_elem(bp[i], bt[i], rp[i], rt[i], accB, accR);
    }
    // wave-64 reduce
    #pragma unroll
    for (int off = 32; off > 0; off >>= 1) {
        accB += __shfl_down(accB, off, 64);
        accR += __shfl_down(accR, off, 64);
    }
    __shared__ float sB[BLOCK / 64], sR[BLOCK / 64];
    const int lane = threadIdx.x & 63;
    const int wid  = threadIdx.x >> 6;
    if (lane == 0) { sB[wid] = accB; sR[wid] = accR; }
    __syncthreads();
    if (threadIdx.x == 0) {
        float b = 0.0f, r = 0.0f;
        #pragma unroll
        for (int w = 0; w < BLOCK / 64; ++w) { b += sB[w]; r += sR[w]; }
        partials[blockIdx.x]        = b;
        partials[GRID + blockIdx.x] = r;
    }
}

__global__ __launch_bounds__(BLOCK) void final_kernel(
    const float* __restrict__ partials, float* __restrict__ out, double invN)
{
    double accB = 0.0, accR = 0.0;
    for (int i = threadIdx.x; i < GRID; i += BLOCK) {
        accB += (double)partials[i];
        accR += (double)partials[GRID + i];
    }
    #pragma unroll
    for (int off = 32; off > 0; off >>= 1) {
        accB += __shfl_down(accB, off, 64);
        accR += __shfl_down(accR, off, 64);
    }
    __shared__ double dB[BLOCK / 64], dR[BLOCK / 64];
    const int lane = threadIdx.x & 63;
    const int wid  = threadIdx.x >> 6;
    if (lane == 0) { dB[wid] = accB; dR[wid] = accR; }
    __syncthreads();
    if (threadIdx.x == 0) {
        double b = 0.0, r = 0.0;
        #pragma unroll
        for (int w = 0; w < BLOCK / 64; ++w) { b += dB[w]; r += dR[w]; }
        const double bm = b * invN;
        const double rm = r * invN;
        out[0] = (float)(bm + rm);  // total = BREAK_W*break + REG_W*reg, both 1.0
        out[1] = (float)bm;         // break_loss
        out[2] = (float)rm;         // regression_loss
    }
}

extern "C" void kernel_launch(void* const* d_in, const int* in_sizes, int n_in,
                              void* d_out, int out_size, void* d_ws, size_t ws_size,
                              hipStream_t stream) {
    // setup_inputs() order: break_predictions, regression_predictions,
    //                       break_targets, regression_targets  (all fp32)
    const float* bp = (const float*)d_in[0];
    const float* rp = (const float*)d_in[1];
    const float* bt = (const float*)d_in[2];
    const float* rt = (const float*)d_in[3];
    const int n  = in_sizes[0];
    const int n4 = n / 4;
    float* partials = (float*)d_ws;   // 2*GRID floats = 16 KB scratch

    partial_kernel<<<GRID, BLOCK, 0, stream>>>(
        (const float4*)bp, (const float4*)rp, (const float4*)bt, (const float4*)rt,
        partials, n4, n);
    final_kernel<<<1, BLOCK, 0, stream>>>(partials, (float*)d_out, 1.0 / (double)n);
}

// Round 2
// 100.970 us; speedup vs baseline: 1.1856x; 1.1856x over previous
//
#include <hip/hip_runtime.h>

// TwoStageRegressionLoss: fused BCE + duration-aware focal smooth-L1 mean
// reduction over N = 2048*16384 fp32 elements per array (4 input arrays).
// 537 MB read -> ~85us floor at 6.3 TB/s. R1 showed libm logf/log1pf made it
// VALU-bound (77% VALUBusy); now uses hw v_log_f32 (log2 * ln2) instead.

constexpr int BLOCK = 256;
constexpr int GRID  = 2048;   // 256 CUs x 8 blocks; 16 float4 iters/thread at N=33.5M

__device__ __forceinline__ void accum_elem(float pv, float tv, float qv, float sv,
                                           float& accB, float& accR) {
    // --- BCE with torch-style log clamp at -100 ---
    constexpr float LN2 = 0.6931471805599453f;
    float pc = fminf(fmaxf(pv, 0.0f), 1.0f);
    float tc = fminf(fmaxf(tv, 0.0f), 1.0f);
    // hw transcendental: v_log_f32 computes log2; log(x) = log2(x)*ln2.
    // log2(0) = -inf -> -inf*ln2 = -inf -> fmax clamps to -100 (matches ref).
    // 1-pc is exact in fp32 for pc>=0.5 (Sterbenz), well-conditioned below,
    // so log(1-pc) ~= log1p(-pc) to ~1e-6 rel; mean threshold is 3e-2.
    float lp  = fmaxf(__log2f(pc)        * LN2, -100.0f);
    float l1p = fmaxf(__log2f(1.0f - pc) * LN2, -100.0f);
    accB -= tc * lp + (1.0f - tc) * l1p;
    // --- duration-aware focal smooth-L1 (alpha=0.25, gamma=2, delta=0.5) ---
    float d = fabsf(qv - sv);
    float f = fminf(d + d, 1.0f);               // clip(d/0.5, 0, 1)
    float base = (d < 0.5f) ? (d * d) : (d - 0.25f);  // smooth L1, beta=0.5
    // class weight: round-half-even (matches jnp.round), clamp [0,3], table {1,4,3,2}
    float r = fminf(fmaxf(__builtin_rintf(sv), 0.0f), 3.0f);
    float w = (r == 0.0f) ? 1.0f : (r == 1.0f) ? 4.0f : (r == 2.0f) ? 3.0f : 2.0f;
    accR += 0.25f * (f * f) * base * w;
}

__global__ __launch_bounds__(BLOCK) void partial_kernel(
    const float4* __restrict__ bp4, const float4* __restrict__ rp4,
    const float4* __restrict__ bt4, const float4* __restrict__ rt4,
    float* __restrict__ partials, int n4, int n)
{
    float accB = 0.0f, accR = 0.0f;
    const int stride = gridDim.x * blockDim.x;
    for (int i = blockIdx.x * blockDim.x + threadIdx.x; i < n4; i += stride) {
        float4 p = bp4[i];
        float4 t = bt4[i];
        float4 q = rp4[i];
        float4 s = rt4[i];
        accum_elem(p.x, t.x, q.x, s.x, accB, accR);
        accum_elem(p.y, t.y, q.y, s.y, accB, accR);
        accum_elem(p.z, t.z, q.z, s.z, accB, accR);
        accum_elem(p.w, t.w, q.w, s.w, accB, accR);
    }
    // scalar tail (n not multiple of 4) -- handled by block 0 only
    if (blockIdx.x == 0) {
        const float* bp = (const float*)bp4;
        const float* bt = (const float*)bt4;
        const float* rp = (const float*)rp4;
        const float* rt = (const float*)rt4;
        for (int i = n4 * 4 + threadIdx.x; i < n; i += BLOCK)
            accum_elem(bp[i], bt[i], rp[i], rt[i], accB, accR);
    }
    // wave-64 reduce
    #pragma unroll
    for (int off = 32; off > 0; off >>= 1) {
        accB += __shfl_down(accB, off, 64);
        accR += __shfl_down(accR, off, 64);
    }
    __shared__ float sB[BLOCK / 64], sR[BLOCK / 64];
    const int lane = threadIdx.x & 63;
    const int wid  = threadIdx.x >> 6;
    if (lane == 0) { sB[wid] = accB; sR[wid] = accR; }
    __syncthreads();
    if (threadIdx.x == 0) {
        float b = 0.0f, r = 0.0f;
        #pragma unroll
        for (int w = 0; w < BLOCK / 64; ++w) { b += sB[w]; r += sR[w]; }
        partials[blockIdx.x]        = b;
        partials[GRID + blockIdx.x] = r;
    }
}

__global__ __launch_bounds__(BLOCK) void final_kernel(
    const float* __restrict__ partials, float* __restrict__ out, double invN)
{
    double accB = 0.0, accR = 0.0;
    for (int i = threadIdx.x; i < GRID; i += BLOCK) {
        accB += (double)partials[i];
        accR += (double)partials[GRID + i];
    }
    #pragma unroll
    for (int off = 32; off > 0; off >>= 1) {
        accB += __shfl_down(accB, off, 64);
        accR += __shfl_down(accR, off, 64);
    }
    __shared__ double dB[BLOCK / 64], dR[BLOCK / 64];
    const int lane = threadIdx.x & 63;
    const int wid  = threadIdx.x >> 6;
    if (lane == 0) { dB[wid] = accB; dR[wid] = accR; }
    __syncthreads();
    if (threadIdx.x == 0) {
        double b = 0.0, r = 0.0;
        #pragma unroll
        for (int w = 0; w < BLOCK / 64; ++w) { b += dB[w]; r += dR[w]; }
        const double bm = b * invN;
        const double rm = r * invN;
        out[0] = (float)(bm + rm);  // total = BREAK_W*break + REG_W*reg, both 1.0
        out[1] = (float)bm;         // break_loss
        out[2] = (float)rm;         // regression_loss
    }
}

extern "C" void kernel_launch(void* const* d_in, const int* in_sizes, int n_in,
                              void* d_out, int out_size, void* d_ws, size_t ws_size,
                              hipStream_t stream) {
    // setup_inputs() order: break_predictions, regression_predictions,
    //                       break_targets, regression_targets  (all fp32)
    const float* bp = (const float*)d_in[0];
    const float* rp = (const float*)d_in[1];
    const float* bt = (const float*)d_in[2];
    const float* rt = (const float*)d_in[3];
    const int n  = in_sizes[0];
    const int n4 = n / 4;
    float* partials = (float*)d_ws;   // 2*GRID floats = 16 KB scratch

    partial_kernel<<<GRID, BLOCK, 0, stream>>>(
        (const float4*)bp, (const float4*)rp, (const float4*)bt, (const float4*)rt,
        partials, n4, n);
    final_kernel<<<1, BLOCK, 0, stream>>>(partials, (float*)d_out, 1.0 / (double)n);
}